// Round 3
// baseline (340.658 us; speedup 1.0000x reference)
//
#include <hip/hip_runtime.h>
#include <math.h>

// ExodusNeuron: per-(b,n) sequential scan over T with spike threshold/reset.
// x: (B=32, T=2048, N=512, 1) fp32; weight: (1,1) fp32; out: (B,T,N,1) fp32.
//
// R2 structure: producer/consumer wave specialization.
//   Only 16384 sequences exist -> 256 compute waves = 1/CU; a single wave's
//   in-order vmcnt queue (<=63 ops) can't hide HBM latency (R0/R1 both ~105us
//   regardless of register pipeline depth). So: 256 blocks x 256 threads;
//   per block wave 0 = consumer (sequential scan, LDS-only), waves 1-3 =
//   producers (HBM->LDS x-tiles, LDS->HBM spike tiles). 3 producer waves
//   give 3x63 outstanding vmem ops per CU; consumer never touches HBM.
//   Double-buffered tiles of 64 steps x 64 neurons (16 KB each, 64 KB LDS).
//
// Numerics MUST match numpy's fp32 rounding exactly (outputs are 0/1 spikes;
// a flipped spike = absmax 1.0): separate rounded mul/add (no FMA), and
// alpha = correctly-rounded float of exp(double(float(-0.05))).
// vmem reset via select(va-1.0f, va) is bitwise identical to va - spk.
// R0/R1 passed with absmax == 0.0 — do not change the arithmetic.

constexpr int B_ = 32;
constexpr int T_ = 2048;
constexpr int N_ = 512;
constexpr int TILE = 64;              // time steps per tile
constexpr int NTILE = T_ / TILE;      // 32 tiles
constexpr int NCHUNK = 64;            // neurons per block

__global__ __launch_bounds__(256, 1)
void exodus_pc_kernel(const float* __restrict__ x,
                      const float* __restrict__ wptr,
                      float* __restrict__ out) {
    __shared__ float XBUF[2][TILE][NCHUNK];   // staged input tiles
    __shared__ float SBUF[2][TILE][NCHUNK];   // staged spike tiles

    const int blk  = blockIdx.x;          // 0..255
    const int b    = blk >> 3;            // 0..31
    const int n0   = (blk & 7) * NCHUNK;  // 0,64,...,448
    const int wave = threadIdx.x >> 6;    // 0..3
    const int lane = threadIdx.x & 63;

    const size_t base = (size_t)b * T_ * N_ + (size_t)n0 + lane;
    const float* __restrict__ xp = x + base;
    float* __restrict__ op = out + base;

    // consumer state (only used by wave 0)
    const float w = wptr[0];
    const float alpha = (float)exp((double)(-1.0f / 20.0f));
    float vsyn = 0.0f, vmem = 0.0f;

    const int wp = wave - 1;              // producer id 0..2 (wave>=1)

    // ---- prologue: producers stage tile 0 ----
    if (wave != 0) {
        for (int j = wp; j < TILE; j += 3)
            XBUF[0][j][lane] = xp[(size_t)j * N_];
    }
    __syncthreads();

    // ---- main pipeline: 33 uniform iterations ----
    for (int t = 0; t <= NTILE; ++t) {
        if (wave != 0) {
            // producers: prefetch tile t+1, drain spikes of tile t-1
            if (t + 1 < NTILE) {
                const float* __restrict__ p = xp + (size_t)(t + 1) * TILE * N_;
                const int bb = (t + 1) & 1;
                for (int j = wp; j < TILE; j += 3)
                    XBUF[bb][j][lane] = p[(size_t)j * N_];
            }
            if (t >= 1) {
                float* __restrict__ o = op + (size_t)(t - 1) * TILE * N_;
                const int bb = (t - 1) & 1;
                for (int j = wp; j < TILE; j += 3)
                    o[(size_t)j * N_] = SBUF[bb][j][lane];
            }
        } else if (t < NTILE) {
            // consumer: sequential scan over tile t, LDS-only
            const int bb = t & 1;
            float xv[TILE];
#pragma unroll
            for (int j = 0; j < TILE; ++j)
                xv[j] = XBUF[bb][j][lane];
#pragma unroll
            for (int j = 0; j < TILE; ++j) {
                const float i_t = __fmul_rn(xv[j], w);
                vsyn = __fadd_rn(__fmul_rn(alpha, vsyn), i_t);
                const float va = __fadd_rn(__fmul_rn(alpha, vmem), vsyn);
                const bool fire = (va >= 1.0f);
                SBUF[bb][j][lane] = fire ? 1.0f : 0.0f;
                vmem = fire ? __fsub_rn(va, 1.0f) : va;  // == va - spk bitwise
            }
        }
        __syncthreads();
    }
}

extern "C" void kernel_launch(void* const* d_in, const int* in_sizes, int n_in,
                              void* d_out, int out_size, void* d_ws, size_t ws_size,
                              hipStream_t stream) {
    const float* x = (const float*)d_in[0];
    const float* w = (const float*)d_in[1];
    float* out = (float*)d_out;

    dim3 grid(256);    // one block (4 waves) per CU; 64 sequences per block
    dim3 block(256);
    hipLaunchKernelGGL(exodus_pc_kernel, grid, block, 0, stream, x, w, out);
}

// Round 4
// 237.947 us; speedup vs baseline: 1.4317x; 1.4317x over previous
//
#include <hip/hip_runtime.h>
#include <math.h>

// ExodusNeuron: per-(b,n) sequential scan over T with spike threshold/reset.
// x: (B=32, T=2048, N=512, 1) fp32; weight: (1,1) fp32; out: (B,T,N,1) fp32.
//
// R3: producer/consumer wave specialization, with BATCHED staging.
//   R2 failed (183us) because the stride-3 runtime-trip producer loops
//   compiled to small load->waitcnt(0)->ds_write groups: one full HBM
//   latency per group, ~6 groups x 33 iters. Fix: 320 threads/block =
//   1 consumer wave + 4 producer waves x exactly 16 rows each, fixed-trip
//   fully-unrolled loops through register arrays so the scheduler hoists
//   all 16 loads before the first ds_write (fine-grained vmcnt waits,
//   one latency per tile, not per load).
//
//   Block owns 64 neurons; tiles of 64 time steps, double-buffered in LDS
//   (XBUF in, SBUF out, 64 KB). One block per CU (256 blocks).
//
// Numerics MUST match numpy's fp32 rounding exactly (outputs are 0/1 spikes;
// a flipped spike = absmax 1.0): separate rounded mul/add (no FMA), and
// alpha = correctly-rounded float of exp(double(float(-0.05))).
// fire ? __fsub_rn(va,1.0f) : va is bitwise identical to va - spk.
// R0/R1/R2 all passed with absmax == 0.0 — do not change the arithmetic.

constexpr int B_ = 32;
constexpr int T_ = 2048;
constexpr int N_ = 512;
constexpr int TILE = 64;               // time steps per tile
constexpr int NTILE = T_ / TILE;       // 32 tiles
constexpr int NCHUNK = 64;             // neurons per block
constexpr int NPROD = 4;               // producer waves
constexpr int RPP = TILE / NPROD;      // 16 rows per producer (exact)

__global__ __launch_bounds__(320, 1)
void exodus_pc_kernel(const float* __restrict__ x,
                      const float* __restrict__ wptr,
                      float* __restrict__ out) {
    __shared__ float XBUF[2][TILE][NCHUNK];   // staged input tiles (32 KB)
    __shared__ float SBUF[2][TILE][NCHUNK];   // staged spike tiles (32 KB)

    const int blk  = blockIdx.x;          // 0..255
    const int b    = blk >> 3;            // 0..31
    const int n0   = (blk & 7) * NCHUNK;  // 0,64,...,448
    const int wave = threadIdx.x >> 6;    // 0..4
    const int lane = threadIdx.x & 63;

    const size_t base = (size_t)b * T_ * N_ + (size_t)n0 + lane;
    const float* __restrict__ xp = x + base;
    float* __restrict__ op = out + base;

    if (wave != 0) {
        // ================= producers =================
        const int p  = wave - 1;          // 0..3
        const int j0 = p * RPP;           // row range [j0, j0+16)

        // prologue: stage tile 0 (batched: 16 loads, then 16 ds_writes)
        {
            const float* __restrict__ g = xp + (size_t)j0 * N_;
            float r[RPP];
#pragma unroll
            for (int i = 0; i < RPP; ++i) r[i] = g[(size_t)i * N_];
#pragma unroll
            for (int i = 0; i < RPP; ++i) XBUF[0][j0 + i][lane] = r[i];
        }
        __syncthreads();

        for (int t = 0; t <= NTILE; ++t) {
            if (t + 1 < NTILE) {
                // prefetch tile t+1: 16 batched loads -> 16 ds_writes
                const float* __restrict__ g =
                    xp + ((size_t)(t + 1) * TILE + j0) * N_;
                const int bb = (t + 1) & 1;
                float r[RPP];
#pragma unroll
                for (int i = 0; i < RPP; ++i) r[i] = g[(size_t)i * N_];
#pragma unroll
                for (int i = 0; i < RPP; ++i) XBUF[bb][j0 + i][lane] = r[i];
            }
            if (t >= 1) {
                // drain spikes of tile t-1: 16 batched ds_reads -> 16 stores
                float* __restrict__ o =
                    op + ((size_t)(t - 1) * TILE + j0) * N_;
                const int bb = (t - 1) & 1;
                float s[RPP];
#pragma unroll
                for (int i = 0; i < RPP; ++i) s[i] = SBUF[bb][j0 + i][lane];
#pragma unroll
                for (int i = 0; i < RPP; ++i) o[(size_t)i * N_] = s[i];
            }
            __syncthreads();
        }
    } else {
        // ================= consumer =================
        const float w = wptr[0];
        const float alpha = (float)exp((double)(-1.0f / 20.0f));
        float vsyn = 0.0f, vmem = 0.0f;

        __syncthreads();   // matches producer prologue barrier

        for (int t = 0; t <= NTILE; ++t) {
            if (t < NTILE) {
                const int bb = t & 1;
                float xv[TILE];
#pragma unroll
                for (int j = 0; j < TILE; ++j)
                    xv[j] = XBUF[bb][j][lane];
#pragma unroll
                for (int j = 0; j < TILE; ++j) {
                    const float i_t = __fmul_rn(xv[j], w);
                    vsyn = __fadd_rn(__fmul_rn(alpha, vsyn), i_t);
                    const float va = __fadd_rn(__fmul_rn(alpha, vmem), vsyn);
                    const bool fire = (va >= 1.0f);
                    SBUF[bb][j][lane] = fire ? 1.0f : 0.0f;
                    vmem = fire ? __fsub_rn(va, 1.0f) : va;  // == va - spk
                }
            }
            __syncthreads();
        }
    }
}

extern "C" void kernel_launch(void* const* d_in, const int* in_sizes, int n_in,
                              void* d_out, int out_size, void* d_ws, size_t ws_size,
                              hipStream_t stream) {
    const float* x = (const float*)d_in[0];
    const float* w = (const float*)d_in[1];
    float* out = (float*)d_out;

    dim3 grid(256);    // one block (5 waves) per CU; 64 sequences per block
    dim3 block(320);
    hipLaunchKernelGGL(exodus_pc_kernel, grid, block, 0, stream, x, w, out);
}